// Round 3
// baseline (481.363 us; speedup 1.0000x reference)
//
#include <hip/hip_runtime.h>
#include <hip/hip_bf16.h>
#include <math.h>

// GAT 3-layer forward for MI355X.
// Device-built dst-CSR each call, then per layer:
//   k_gemm_alpha: h = x@W + per-(node,head) attention logits (alpha_src/dst)
//   k_agg: per-node online segment-softmax + gather-aggregate (no float atomics)

#define NEG_SLOPE 0.2f

// ---------------- CSR build ----------------

__global__ void k_init_deg(int* __restrict__ deg, int n) {
    int i = blockIdx.x * blockDim.x + threadIdx.x;
    if (i < n) deg[i] = 1;  // self-loop
}

__global__ void k_count(const int* __restrict__ idx, int* __restrict__ deg, int E) {
    int e = blockIdx.x * blockDim.x + threadIdx.x;
    if (e < E) atomicAdd(&deg[idx[E + e]], 1);  // dst row
}

// single-block exclusive scan over deg[0..n) -> off, cur
__global__ void k_scan(const int* __restrict__ deg, int* __restrict__ off,
                       int* __restrict__ cur, int n, int etot) {
    __shared__ int part[1024];
    int t = threadIdx.x;
    int chunk = (n + 1023) >> 10;
    int b = t * chunk;
    int e = b + chunk; if (e > n) e = n;
    int s = 0;
    for (int i = b; i < e; ++i) s += deg[i];
    part[t] = s;
    __syncthreads();
    for (int o = 1; o < 1024; o <<= 1) {
        int v = (t >= o) ? part[t - o] : 0;
        __syncthreads();
        part[t] += v;
        __syncthreads();
    }
    int run = (t == 0) ? 0 : part[t - 1];
    for (int i = b; i < e; ++i) {
        off[i] = run; cur[i] = run;
        run += deg[i];
    }
    if (t == 0) off[n] = etot;
}

__global__ void k_scatter(const int* __restrict__ idx, int* __restrict__ cur,
                          int* __restrict__ csr_src, int E, int n) {
    int e = blockIdx.x * blockDim.x + threadIdx.x;
    int etot = E + n;
    if (e >= etot) return;
    int s, d;
    if (e < E) { s = idx[e]; d = idx[E + e]; }
    else       { s = d = e - E; }
    int pos = atomicAdd(&cur[d], 1);
    csr_src[pos] = s;
}

// ---------------- per-layer compute ----------------

// h = x @ W  [n, 64]; plus alpha_src/alpha_dst per (node, head).
// 256-thread block = 4 waves; block owns 16 nodes; each wave computes 4 nodes
// (all 64 output cols, lane = col), amortizing each W load over 4 fma chains.
template <int K, int H, int F>
__global__ __launch_bounds__(256) void k_gemm_alpha(
    const float* __restrict__ x, const float* __restrict__ W,
    const float* __restrict__ a_s, const float* __restrict__ a_d,
    float* __restrict__ h, float* __restrict__ as_o, float* __restrict__ ad_o,
    int n) {
    __shared__ float xs[16][K];
    const int tid = threadIdx.x;
    const int base = blockIdx.x * 16;
    int rows = n - base; if (rows > 16) rows = 16;
    const int kv = K / 4;
    for (int i = tid; i < rows * kv; i += 256) {
        int r = i / kv, c = i - r * kv;
        ((float4*)&xs[r][0])[c] = ((const float4*)(x + (size_t)(base + r) * K))[c];
    }
    __syncthreads();
    const int w = tid >> 6, lane = tid & 63;
    const int node0 = base + w * 4;
    float acc0 = 0.f, acc1 = 0.f, acc2 = 0.f, acc3 = 0.f;
    #pragma unroll 4
    for (int k = 0; k < K; ++k) {
        float wv = W[k * 64 + lane];
        acc0 = fmaf(xs[w * 4 + 0][k], wv, acc0);
        acc1 = fmaf(xs[w * 4 + 1][k], wv, acc1);
        acc2 = fmaf(xs[w * 4 + 2][k], wv, acc2);
        acc3 = fmaf(xs[w * 4 + 3][k], wv, acc3);
    }
    const int head = (H == 1) ? 0 : (lane >> 4);
    const int f = (H == 1) ? lane : (lane & (F - 1));
    const float asv = a_s[head * F + f];
    const float adv = a_d[head * F + f];
    float accs[4] = {acc0, acc1, acc2, acc3};
    #pragma unroll
    for (int j = 0; j < 4; ++j) {
        int node = node0 + j;
        if (node >= n) break;
        h[(size_t)node * 64 + lane] = accs[j];
        float vs = accs[j] * asv;
        float vd = accs[j] * adv;
        #pragma unroll
        for (int o = F >> 1; o > 0; o >>= 1) {
            vs += __shfl_xor(vs, o);
            vd += __shfl_xor(vd, o);
        }
        if (f == 0) {
            as_o[node * H + head] = vs;
            ad_o[node * H + head] = vd;
        }
    }
}

// Per-node online segment softmax + gather aggregate. One wave per node.
// Quarter q (16 lanes) owns edges b+q, b+q+4, ...; lane c4 in each quarter
// owns output cols 4*c4..4*c4+3 (float4). Cross-quarter combine at the end.
// Inner loop is software-pipelined 1 deep: next edge's (csr, as_b) gathers
// are issued before the current edge's h-row fetch + exp/fma math.
template <int H, bool ELU>
__global__ __launch_bounds__(256) void k_agg(
    const float* __restrict__ h, const float* __restrict__ as_b,
    const float* __restrict__ ad_b, const int* __restrict__ off,
    const int* __restrict__ csr, const float* __restrict__ bias,
    float* __restrict__ out, int n) {
    const int w = threadIdx.x >> 6, lane = threadIdx.x & 63;
    const int node = blockIdx.x * 4 + w;
    if (node >= n) return;
    const int q = lane >> 4;
    const int c4 = lane & 15;
    const int head = (H == 1) ? 0 : (c4 >> 2);
    const float ad_n = ad_b[node * H + head];
    const int b = off[node], e = off[node + 1];
    float m = -1e30f, den = 0.f;
    float4 acc = {0.f, 0.f, 0.f, 0.f};
    int p = b + q;
    int s_cur = 0; float as_cur = 0.f;
    if (p < e) {
        s_cur = csr[p];
        as_cur = as_b[s_cur * H + head];
    }
    while (p < e) {
        const int pn = p + 4;
        int s_nxt = 0; float as_nxt = 0.f;
        if (pn < e) {                      // prefetch next edge's chain
            s_nxt = csr[pn];
            as_nxt = as_b[s_nxt * H + head];
        }
        float ev = as_cur + ad_n;
        ev = ev > 0.f ? ev : NEG_SLOPE * ev;
        float mn = fmaxf(m, ev);
        float sc = __expf(m - mn);         // 1 if max unchanged; 0 on first edge
        float wv = __expf(ev - mn);
        m = mn;
        const float4 hv = *(const float4*)(h + (size_t)s_cur * 64 + c4 * 4);
        den = fmaf(den, sc, wv);
        acc.x = fmaf(acc.x, sc, wv * hv.x);
        acc.y = fmaf(acc.y, sc, wv * hv.y);
        acc.z = fmaf(acc.z, sc, wv * hv.z);
        acc.w = fmaf(acc.w, sc, wv * hv.w);
        p = pn; s_cur = s_nxt; as_cur = as_nxt;
    }
    // combine quarters (align maxes, then butterfly-sum over lane bits 4,5)
    float m2 = fmaxf(m, __shfl_xor(m, 16));
    float mt = fmaxf(m2, __shfl_xor(m2, 32));
    float sc = __expf(m - mt);             // 0 for empty quarters (m = -1e30)
    den *= sc; acc.x *= sc; acc.y *= sc; acc.z *= sc; acc.w *= sc;
    den += __shfl_xor(den, 16); den += __shfl_xor(den, 32);
    acc.x += __shfl_xor(acc.x, 16); acc.x += __shfl_xor(acc.x, 32);
    acc.y += __shfl_xor(acc.y, 16); acc.y += __shfl_xor(acc.y, 32);
    acc.z += __shfl_xor(acc.z, 16); acc.z += __shfl_xor(acc.z, 32);
    acc.w += __shfl_xor(acc.w, 16); acc.w += __shfl_xor(acc.w, 32);
    if (q == 0) {
        float inv = 1.f / (den + 1e-16f);
        float4 r;
        r.x = acc.x * inv + bias[c4 * 4 + 0];
        r.y = acc.y * inv + bias[c4 * 4 + 1];
        r.z = acc.z * inv + bias[c4 * 4 + 2];
        r.w = acc.w * inv + bias[c4 * 4 + 3];
        if (ELU) {
            r.x = r.x > 0.f ? r.x : expm1f(r.x);
            r.y = r.y > 0.f ? r.y : expm1f(r.y);
            r.z = r.z > 0.f ? r.z : expm1f(r.z);
            r.w = r.w > 0.f ? r.w : expm1f(r.w);
        }
        *(float4*)(out + (size_t)node * 64 + c4 * 4) = r;
    }
}

// ---------------- launch ----------------

extern "C" void kernel_launch(void* const* d_in, const int* in_sizes, int n_in,
                              void* d_out, int out_size, void* d_ws, size_t ws_size,
                              hipStream_t stream) {
    const float* x   = (const float*)d_in[0];
    const int*   idx = (const int*)d_in[1];
    const float* W0  = (const float*)d_in[2];
    const float* as0 = (const float*)d_in[3];
    const float* ad0 = (const float*)d_in[4];
    const float* b0  = (const float*)d_in[5];
    const float* W1  = (const float*)d_in[6];
    const float* as1 = (const float*)d_in[7];
    const float* ad1 = (const float*)d_in[8];
    const float* b1  = (const float*)d_in[9];
    const float* W2  = (const float*)d_in[10];
    const float* as2 = (const float*)d_in[11];
    const float* ad2 = (const float*)d_in[12];
    const float* b2  = (const float*)d_in[13];
    float* out = (float*)d_out;

    const int n    = in_sizes[0] / 128;   // 50000
    const int E    = in_sizes[1] / 2;     // 800000
    const int etot = E + n;

    char* p = (char*)d_ws;
    auto alloc = [&](size_t bytes) {
        char* r = p;
        p += (bytes + 255) & ~(size_t)255;
        return r;
    };
    int*   deg = (int*)alloc((size_t)n * 4);
    int*   off = (int*)alloc((size_t)(n + 1) * 4);
    int*   cur = (int*)alloc((size_t)n * 4);
    int*   csr = (int*)alloc((size_t)etot * 4);
    float* asb = (float*)alloc((size_t)n * 4 * 4);
    float* adb = (float*)alloc((size_t)n * 4 * 4);
    float* hA  = (float*)alloc((size_t)n * 64 * 4);
    // d_out doubles as the inter-layer activation buffer (N*64 floats).

    const int nb_n  = (n + 255) / 256;
    const int nb_e  = (E + 255) / 256;
    const int nb_et = (etot + 255) / 256;
    const int nb_g  = (n + 15) / 16;   // gemm: 16 nodes / block
    const int nb_w  = (n + 3) / 4;     // agg: 4 nodes (waves) / block

    // CSR build (every call; ws is re-poisoned by the harness)
    k_init_deg<<<nb_n, 256, 0, stream>>>(deg, n);
    k_count<<<nb_e, 256, 0, stream>>>(idx, deg, E);
    k_scan<<<1, 1024, 0, stream>>>(deg, off, cur, n, etot);
    k_scatter<<<nb_et, 256, 0, stream>>>(idx, cur, csr, E, n);

    // layer 0: 128 -> (4,16), concat, ELU   (x -> hA -> out)
    k_gemm_alpha<128, 4, 16><<<nb_g, 256, 0, stream>>>(x, W0, as0, ad0, hA, asb, adb, n);
    k_agg<4, true><<<nb_w, 256, 0, stream>>>(hA, asb, adb, off, csr, b0, out, n);

    // layer 1: 64 -> (4,16), concat, ELU    (out -> hA -> out)
    k_gemm_alpha<64, 4, 16><<<nb_g, 256, 0, stream>>>(out, W1, as1, ad1, hA, asb, adb, n);
    k_agg<4, true><<<nb_w, 256, 0, stream>>>(hA, asb, adb, off, csr, b1, out, n);

    // layer 2: 64 -> (1,64), mean(=identity), no ELU   (out -> hA -> out)
    k_gemm_alpha<64, 1, 64><<<nb_g, 256, 0, stream>>>(out, W2, as2, ad2, hA, asb, adb, n);
    k_agg<1, false><<<nb_w, 256, 0, stream>>>(hA, asb, adb, off, csr, b2, out, n);
}

// Round 4
// 381.653 us; speedup vs baseline: 1.2613x; 1.2613x over previous
//
#include <hip/hip_runtime.h>
#include <hip/hip_bf16.h>
#include <math.h>

// GAT 3-layer forward for MI355X.
// Device-built dst-CSR each call, then per layer:
//   k_gemm_alpha: h = x@W + per-(node,head) attention logits (alpha_src/dst)
//   k_agg: per-node online segment-softmax + gather-aggregate (no float atomics)
// R3: replaced single-block scan (110 us, 0.14% occupancy) with 3-phase
// hierarchical scan (49 blocks x 1024 elems).

#define NEG_SLOPE 0.2f
#define SCAN_CHUNK 1024

// ---------------- CSR build ----------------

__global__ void k_init_deg(int* __restrict__ deg, int n) {
    int i = blockIdx.x * blockDim.x + threadIdx.x;
    if (i < n) deg[i] = 1;  // self-loop
}

__global__ void k_count(const int* __restrict__ idx, int* __restrict__ deg, int E) {
    int e = blockIdx.x * blockDim.x + threadIdx.x;
    if (e < E) atomicAdd(&deg[idx[E + e]], 1);  // dst row
}

// phase 1: per-block (1024-elem chunk) sums
__global__ void k_scan_p1(const int* __restrict__ deg, int* __restrict__ bsum, int n) {
    __shared__ int sdata[256];
    const int t = threadIdx.x;
    const int base = blockIdx.x * SCAN_CHUNK + t * 4;
    int s = 0;
    #pragma unroll
    for (int j = 0; j < 4; ++j) {
        int i = base + j;
        if (i < n) s += deg[i];
    }
    sdata[t] = s;
    __syncthreads();
    for (int o = 128; o > 0; o >>= 1) {
        if (t < o) sdata[t] += sdata[t + o];
        __syncthreads();
    }
    if (t == 0) bsum[blockIdx.x] = sdata[0];
}

// phase 2: single-block exclusive scan over nb block sums (nb <= 256)
__global__ void k_scan_p2(int* __restrict__ bsum, int nb) {
    __shared__ int sh[256];
    const int t = threadIdx.x;
    sh[t] = (t < nb) ? bsum[t] : 0;
    __syncthreads();
    for (int o = 1; o < 256; o <<= 1) {
        int v = (t >= o) ? sh[t - o] : 0;
        __syncthreads();
        sh[t] += v;
        __syncthreads();
    }
    if (t < nb) bsum[t] = (t == 0) ? 0 : sh[t - 1];
}

// phase 3: intra-chunk exclusive scan + block offset -> off, cur
__global__ void k_scan_p3(const int* __restrict__ deg, const int* __restrict__ bsum,
                          int* __restrict__ off, int* __restrict__ cur,
                          int n, int etot) {
    __shared__ int sdata[256];
    const int t = threadIdx.x;
    const int base = blockIdx.x * SCAN_CHUNK + t * 4;
    int v[4];
    int s = 0;
    #pragma unroll
    for (int j = 0; j < 4; ++j) {
        int i = base + j;
        v[j] = (i < n) ? deg[i] : 0;
        s += v[j];
    }
    sdata[t] = s;
    __syncthreads();
    for (int o = 1; o < 256; o <<= 1) {
        int x = (t >= o) ? sdata[t - o] : 0;
        __syncthreads();
        sdata[t] += x;
        __syncthreads();
    }
    int run = bsum[blockIdx.x] + ((t == 0) ? 0 : sdata[t - 1]);
    #pragma unroll
    for (int j = 0; j < 4; ++j) {
        int i = base + j;
        if (i < n) { off[i] = run; cur[i] = run; run += v[j]; }
    }
    if (blockIdx.x == 0 && t == 0) off[n] = etot;
}

__global__ void k_scatter(const int* __restrict__ idx, int* __restrict__ cur,
                          int* __restrict__ csr_src, int E, int n) {
    int e = blockIdx.x * blockDim.x + threadIdx.x;
    int etot = E + n;
    if (e >= etot) return;
    int s, d;
    if (e < E) { s = idx[e]; d = idx[E + e]; }
    else       { s = d = e - E; }
    int pos = atomicAdd(&cur[d], 1);
    csr_src[pos] = s;
}

// ---------------- per-layer compute ----------------

// h = x @ W  [n, 64]; plus alpha_src/alpha_dst per (node, head).
// 256-thread block = 4 waves; block owns 16 nodes; each wave computes 4 nodes
// (all 64 output cols, lane = col), amortizing each W load over 4 fma chains.
template <int K, int H, int F>
__global__ __launch_bounds__(256) void k_gemm_alpha(
    const float* __restrict__ x, const float* __restrict__ W,
    const float* __restrict__ a_s, const float* __restrict__ a_d,
    float* __restrict__ h, float* __restrict__ as_o, float* __restrict__ ad_o,
    int n) {
    __shared__ float xs[16][K];
    const int tid = threadIdx.x;
    const int base = blockIdx.x * 16;
    int rows = n - base; if (rows > 16) rows = 16;
    const int kv = K / 4;
    for (int i = tid; i < rows * kv; i += 256) {
        int r = i / kv, c = i - r * kv;
        ((float4*)&xs[r][0])[c] = ((const float4*)(x + (size_t)(base + r) * K))[c];
    }
    __syncthreads();
    const int w = tid >> 6, lane = tid & 63;
    const int node0 = base + w * 4;
    float acc0 = 0.f, acc1 = 0.f, acc2 = 0.f, acc3 = 0.f;
    #pragma unroll 4
    for (int k = 0; k < K; ++k) {
        float wv = W[k * 64 + lane];
        acc0 = fmaf(xs[w * 4 + 0][k], wv, acc0);
        acc1 = fmaf(xs[w * 4 + 1][k], wv, acc1);
        acc2 = fmaf(xs[w * 4 + 2][k], wv, acc2);
        acc3 = fmaf(xs[w * 4 + 3][k], wv, acc3);
    }
    const int head = (H == 1) ? 0 : (lane >> 4);
    const int f = (H == 1) ? lane : (lane & (F - 1));
    const float asv = a_s[head * F + f];
    const float adv = a_d[head * F + f];
    float accs[4] = {acc0, acc1, acc2, acc3};
    #pragma unroll
    for (int j = 0; j < 4; ++j) {
        int node = node0 + j;
        if (node >= n) break;
        h[(size_t)node * 64 + lane] = accs[j];
        float vs = accs[j] * asv;
        float vd = accs[j] * adv;
        #pragma unroll
        for (int o = F >> 1; o > 0; o >>= 1) {
            vs += __shfl_xor(vs, o);
            vd += __shfl_xor(vd, o);
        }
        if (f == 0) {
            as_o[node * H + head] = vs;
            ad_o[node * H + head] = vd;
        }
    }
}

// Per-node online segment softmax + gather aggregate. One wave per node.
// Quarter q (16 lanes) owns edges b+q, b+q+4, ...; lane c4 in each quarter
// owns output cols 4*c4..4*c4+3 (float4). Cross-quarter combine at the end.
// Inner loop is software-pipelined 1 deep: next edge's (csr, as_b) gathers
// are issued before the current edge's h-row fetch + exp/fma math.
template <int H, bool ELU>
__global__ __launch_bounds__(256) void k_agg(
    const float* __restrict__ h, const float* __restrict__ as_b,
    const float* __restrict__ ad_b, const int* __restrict__ off,
    const int* __restrict__ csr, const float* __restrict__ bias,
    float* __restrict__ out, int n) {
    const int w = threadIdx.x >> 6, lane = threadIdx.x & 63;
    const int node = blockIdx.x * 4 + w;
    if (node >= n) return;
    const int q = lane >> 4;
    const int c4 = lane & 15;
    const int head = (H == 1) ? 0 : (c4 >> 2);
    const float ad_n = ad_b[node * H + head];
    const int b = off[node], e = off[node + 1];
    float m = -1e30f, den = 0.f;
    float4 acc = {0.f, 0.f, 0.f, 0.f};
    int p = b + q;
    int s_cur = 0; float as_cur = 0.f;
    if (p < e) {
        s_cur = csr[p];
        as_cur = as_b[s_cur * H + head];
    }
    while (p < e) {
        const int pn = p + 4;
        int s_nxt = 0; float as_nxt = 0.f;
        if (pn < e) {                      // prefetch next edge's chain
            s_nxt = csr[pn];
            as_nxt = as_b[s_nxt * H + head];
        }
        float ev = as_cur + ad_n;
        ev = ev > 0.f ? ev : NEG_SLOPE * ev;
        float mn = fmaxf(m, ev);
        float sc = __expf(m - mn);         // 1 if max unchanged; 0 on first edge
        float wv = __expf(ev - mn);
        m = mn;
        const float4 hv = *(const float4*)(h + (size_t)s_cur * 64 + c4 * 4);
        den = fmaf(den, sc, wv);
        acc.x = fmaf(acc.x, sc, wv * hv.x);
        acc.y = fmaf(acc.y, sc, wv * hv.y);
        acc.z = fmaf(acc.z, sc, wv * hv.z);
        acc.w = fmaf(acc.w, sc, wv * hv.w);
        p = pn; s_cur = s_nxt; as_cur = as_nxt;
    }
    // combine quarters (align maxes, then butterfly-sum over lane bits 4,5)
    float m2 = fmaxf(m, __shfl_xor(m, 16));
    float mt = fmaxf(m2, __shfl_xor(m2, 32));
    float sc = __expf(m - mt);             // 0 for empty quarters (m = -1e30)
    den *= sc; acc.x *= sc; acc.y *= sc; acc.z *= sc; acc.w *= sc;
    den += __shfl_xor(den, 16); den += __shfl_xor(den, 32);
    acc.x += __shfl_xor(acc.x, 16); acc.x += __shfl_xor(acc.x, 32);
    acc.y += __shfl_xor(acc.y, 16); acc.y += __shfl_xor(acc.y, 32);
    acc.z += __shfl_xor(acc.z, 16); acc.z += __shfl_xor(acc.z, 32);
    acc.w += __shfl_xor(acc.w, 16); acc.w += __shfl_xor(acc.w, 32);
    if (q == 0) {
        float inv = 1.f / (den + 1e-16f);
        float4 r;
        r.x = acc.x * inv + bias[c4 * 4 + 0];
        r.y = acc.y * inv + bias[c4 * 4 + 1];
        r.z = acc.z * inv + bias[c4 * 4 + 2];
        r.w = acc.w * inv + bias[c4 * 4 + 3];
        if (ELU) {
            r.x = r.x > 0.f ? r.x : expm1f(r.x);
            r.y = r.y > 0.f ? r.y : expm1f(r.y);
            r.z = r.z > 0.f ? r.z : expm1f(r.z);
            r.w = r.w > 0.f ? r.w : expm1f(r.w);
        }
        *(float4*)(out + (size_t)node * 64 + c4 * 4) = r;
    }
}

// ---------------- launch ----------------

extern "C" void kernel_launch(void* const* d_in, const int* in_sizes, int n_in,
                              void* d_out, int out_size, void* d_ws, size_t ws_size,
                              hipStream_t stream) {
    const float* x   = (const float*)d_in[0];
    const int*   idx = (const int*)d_in[1];
    const float* W0  = (const float*)d_in[2];
    const float* as0 = (const float*)d_in[3];
    const float* ad0 = (const float*)d_in[4];
    const float* b0  = (const float*)d_in[5];
    const float* W1  = (const float*)d_in[6];
    const float* as1 = (const float*)d_in[7];
    const float* ad1 = (const float*)d_in[8];
    const float* b1  = (const float*)d_in[9];
    const float* W2  = (const float*)d_in[10];
    const float* as2 = (const float*)d_in[11];
    const float* ad2 = (const float*)d_in[12];
    const float* b2  = (const float*)d_in[13];
    float* out = (float*)d_out;

    const int n    = in_sizes[0] / 128;   // 50000
    const int E    = in_sizes[1] / 2;     // 800000
    const int etot = E + n;

    char* p = (char*)d_ws;
    auto alloc = [&](size_t bytes) {
        char* r = p;
        p += (bytes + 255) & ~(size_t)255;
        return r;
    };
    int*   deg  = (int*)alloc((size_t)n * 4);
    int*   off  = (int*)alloc((size_t)(n + 1) * 4);
    int*   cur  = (int*)alloc((size_t)n * 4);
    int*   csr  = (int*)alloc((size_t)etot * 4);
    int*   bsum = (int*)alloc(256 * 4);
    float* asb  = (float*)alloc((size_t)n * 4 * 4);
    float* adb  = (float*)alloc((size_t)n * 4 * 4);
    float* hA   = (float*)alloc((size_t)n * 64 * 4);
    // d_out doubles as the inter-layer activation buffer (N*64 floats).

    const int nb_n  = (n + 255) / 256;
    const int nb_e  = (E + 255) / 256;
    const int nb_et = (etot + 255) / 256;
    const int nb_s  = (n + SCAN_CHUNK - 1) / SCAN_CHUNK;  // 49 scan blocks
    const int nb_g  = (n + 15) / 16;   // gemm: 16 nodes / block
    const int nb_w  = (n + 3) / 4;     // agg: 4 nodes (waves) / block

    // CSR build (every call; ws is re-poisoned by the harness)
    k_init_deg<<<nb_n, 256, 0, stream>>>(deg, n);
    k_count<<<nb_e, 256, 0, stream>>>(idx, deg, E);
    k_scan_p1<<<nb_s, 256, 0, stream>>>(deg, bsum, n);
    k_scan_p2<<<1, 256, 0, stream>>>(bsum, nb_s);
    k_scan_p3<<<nb_s, 256, 0, stream>>>(deg, bsum, off, cur, n, etot);
    k_scatter<<<nb_et, 256, 0, stream>>>(idx, cur, csr, E, n);

    // layer 0: 128 -> (4,16), concat, ELU   (x -> hA -> out)
    k_gemm_alpha<128, 4, 16><<<nb_g, 256, 0, stream>>>(x, W0, as0, ad0, hA, asb, adb, n);
    k_agg<4, true><<<nb_w, 256, 0, stream>>>(hA, asb, adb, off, csr, b0, out, n);

    // layer 1: 64 -> (4,16), concat, ELU    (out -> hA -> out)
    k_gemm_alpha<64, 4, 16><<<nb_g, 256, 0, stream>>>(out, W1, as1, ad1, hA, asb, adb, n);
    k_agg<4, true><<<nb_w, 256, 0, stream>>>(hA, asb, adb, off, csr, b1, out, n);

    // layer 2: 64 -> (1,64), mean(=identity), no ELU   (out -> hA -> out)
    k_gemm_alpha<64, 1, 64><<<nb_g, 256, 0, stream>>>(out, W2, as2, ad2, hA, asb, adb, n);
    k_agg<1, false><<<nb_w, 256, 0, stream>>>(hA, asb, adb, off, csr, b2, out, n);
}

// Round 5
// 319.875 us; speedup vs baseline: 1.5048x; 1.1931x over previous
//
#include <hip/hip_runtime.h>
#include <hip/hip_bf16.h>
#include <math.h>

// GAT 3-layer forward for MI355X.
// R4: CSR build rewritten as two-level partition (256 coarse buckets by
// dst>>8, then per-bucket exact-dst LDS counting sort). Removes the 50K-bin
// global atomic histogram + random scatter (was ~125 us, 54 MB HBM writes).
// Then per layer: k_gemm_alpha (h = x@W + logits), k_agg (online segment
// softmax + gather aggregate, no float atomics).

#define NEG_SLOPE 0.2f
#define L1_CHUNK 4096

// ---------------- two-level CSR build ----------------

// phase 1: global coarse histogram (bucket = dst>>8)
__global__ __launch_bounds__(256) void k_l1hist(
    const int* __restrict__ idx, int* __restrict__ ghist, int E, int etot) {
    __shared__ int h[256];
    const int t = threadIdx.x;
    h[t] = 0;
    __syncthreads();
    const int base = blockIdx.x * L1_CHUNK;
    for (int i = t; i < L1_CHUNK; i += 256) {
        int e = base + i;
        if (e >= etot) break;
        int dst = (e < E) ? idx[E + e] : (e - E);
        atomicAdd(&h[dst >> 8], 1);
    }
    __syncthreads();
    if (h[t]) atomicAdd(&ghist[t], h[t]);
}

// phase 2: 1-block exclusive scan of 256 bucket counts -> goff[257], gcur
__global__ __launch_bounds__(256) void k_scan256(
    const int* __restrict__ ghist, int* __restrict__ goff, int* __restrict__ gcur) {
    __shared__ int sc[256];
    const int t = threadIdx.x;
    int v = ghist[t];
    sc[t] = v;
    __syncthreads();
    for (int o = 1; o < 256; o <<= 1) {
        int x = (t >= o) ? sc[t - o] : 0;
        __syncthreads();
        sc[t] += x;
        __syncthreads();
    }
    int excl = sc[t] - v;
    goff[t] = excl;
    gcur[t] = excl;
    if (t == 255) goff[256] = sc[255];
}

// phase 3: scatter packed (dst,src) into bucket-contiguous buf.
// Per block: LDS hist, one global reserve atomic per nonzero bin, LDS-ranked
// writes (order within a bucket is arbitrary - fine, sums are order-free).
__global__ __launch_bounds__(256) void k_l1scatter(
    const int* __restrict__ idx, int* __restrict__ gcur,
    unsigned long long* __restrict__ buf, int E, int etot) {
    __shared__ int h[256];
    __shared__ int lbase[256];
    const int t = threadIdx.x;
    h[t] = 0;
    __syncthreads();
    const int base = blockIdx.x * L1_CHUNK;
    for (int i = t; i < L1_CHUNK; i += 256) {
        int e = base + i;
        if (e >= etot) break;
        int dst = (e < E) ? idx[E + e] : (e - E);
        atomicAdd(&h[dst >> 8], 1);
    }
    __syncthreads();
    lbase[t] = h[t] ? atomicAdd(&gcur[t], h[t]) : 0;
    __syncthreads();
    h[t] = lbase[t];   // reuse h as absolute running cursor
    __syncthreads();
    for (int i = t; i < L1_CHUNK; i += 256) {
        int e = base + i;
        if (e >= etot) break;
        int dst, src;
        if (e < E) { dst = idx[E + e]; src = idx[e]; }
        else       { dst = src = e - E; }
        int pos = atomicAdd(&h[dst >> 8], 1);
        buf[pos] = ((unsigned long long)(unsigned)dst << 32) | (unsigned)src;
    }
}

// phase 4: one block per bucket - exact-dst counting sort within the bucket,
// writes off[] and final csr[] (all within one contiguous ~17KB window).
__global__ __launch_bounds__(256) void k_l2build(
    const unsigned long long* __restrict__ buf, const int* __restrict__ goff,
    int* __restrict__ off, int* __restrict__ csr, int n, int etot) {
    __shared__ int sc[256];
    __shared__ int lcur[256];
    const int b = blockIdx.x, t = threadIdx.x;
    const int lo = goff[b], hi = goff[b + 1];
    sc[t] = 0;
    __syncthreads();
    for (int p = lo + t; p < hi; p += 256) {
        int dst = (int)(buf[p] >> 32);
        atomicAdd(&sc[dst & 255], 1);
    }
    __syncthreads();
    int v = sc[t];
    __syncthreads();
    // exclusive scan over 256 bins
    sc[t] = v;
    __syncthreads();
    for (int o = 1; o < 256; o <<= 1) {
        int x = (t >= o) ? sc[t - o] : 0;
        __syncthreads();
        sc[t] += x;
        __syncthreads();
    }
    int excl = sc[t] - v;
    const int d = b * 256 + t;
    if (d < n) off[d] = lo + excl;
    lcur[t] = lo + excl;
    __syncthreads();
    for (int p = lo + t; p < hi; p += 256) {
        unsigned long long e = buf[p];
        int dst = (int)(e >> 32);
        int src = (int)(e & 0xffffffffu);
        int pos = atomicAdd(&lcur[dst & 255], 1);
        csr[pos] = src;
    }
    if (b == 0 && t == 0) off[n] = etot;
}

// ---------------- per-layer compute ----------------

// h = x @ W  [n, 64]; plus alpha_src/alpha_dst per (node, head).
// 256-thread block = 4 waves; block owns 16 nodes; each wave computes 4 nodes
// (all 64 output cols, lane = col), amortizing each W load over 4 fma chains.
template <int K, int H, int F>
__global__ __launch_bounds__(256) void k_gemm_alpha(
    const float* __restrict__ x, const float* __restrict__ W,
    const float* __restrict__ a_s, const float* __restrict__ a_d,
    float* __restrict__ h, float* __restrict__ as_o, float* __restrict__ ad_o,
    int n) {
    __shared__ float xs[16][K];
    const int tid = threadIdx.x;
    const int base = blockIdx.x * 16;
    int rows = n - base; if (rows > 16) rows = 16;
    const int kv = K / 4;
    for (int i = tid; i < rows * kv; i += 256) {
        int r = i / kv, c = i - r * kv;
        ((float4*)&xs[r][0])[c] = ((const float4*)(x + (size_t)(base + r) * K))[c];
    }
    __syncthreads();
    const int w = tid >> 6, lane = tid & 63;
    const int node0 = base + w * 4;
    float acc0 = 0.f, acc1 = 0.f, acc2 = 0.f, acc3 = 0.f;
    #pragma unroll 4
    for (int k = 0; k < K; ++k) {
        float wv = W[k * 64 + lane];
        acc0 = fmaf(xs[w * 4 + 0][k], wv, acc0);
        acc1 = fmaf(xs[w * 4 + 1][k], wv, acc1);
        acc2 = fmaf(xs[w * 4 + 2][k], wv, acc2);
        acc3 = fmaf(xs[w * 4 + 3][k], wv, acc3);
    }
    const int head = (H == 1) ? 0 : (lane >> 4);
    const int f = (H == 1) ? lane : (lane & (F - 1));
    const float asv = a_s[head * F + f];
    const float adv = a_d[head * F + f];
    float accs[4] = {acc0, acc1, acc2, acc3};
    #pragma unroll
    for (int j = 0; j < 4; ++j) {
        int node = node0 + j;
        if (node >= n) break;
        h[(size_t)node * 64 + lane] = accs[j];
        float vs = accs[j] * asv;
        float vd = accs[j] * adv;
        #pragma unroll
        for (int o = F >> 1; o > 0; o >>= 1) {
            vs += __shfl_xor(vs, o);
            vd += __shfl_xor(vd, o);
        }
        if (f == 0) {
            as_o[node * H + head] = vs;
            ad_o[node * H + head] = vd;
        }
    }
}

// Per-node online segment softmax + gather aggregate. One wave per node.
// Quarter q (16 lanes) owns edges b+q, b+q+4, ...; lane c4 in each quarter
// owns output cols 4*c4..4*c4+3 (float4). Cross-quarter combine at the end.
// Inner loop is software-pipelined 1 deep: next edge's (csr, as_b) gathers
// are issued before the current edge's h-row fetch + exp/fma math.
template <int H, bool ELU>
__global__ __launch_bounds__(256) void k_agg(
    const float* __restrict__ h, const float* __restrict__ as_b,
    const float* __restrict__ ad_b, const int* __restrict__ off,
    const int* __restrict__ csr, const float* __restrict__ bias,
    float* __restrict__ out, int n) {
    const int w = threadIdx.x >> 6, lane = threadIdx.x & 63;
    const int node = blockIdx.x * 4 + w;
    if (node >= n) return;
    const int q = lane >> 4;
    const int c4 = lane & 15;
    const int head = (H == 1) ? 0 : (c4 >> 2);
    const float ad_n = ad_b[node * H + head];
    const int b = off[node], e = off[node + 1];
    float m = -1e30f, den = 0.f;
    float4 acc = {0.f, 0.f, 0.f, 0.f};
    int p = b + q;
    int s_cur = 0; float as_cur = 0.f;
    if (p < e) {
        s_cur = csr[p];
        as_cur = as_b[s_cur * H + head];
    }
    while (p < e) {
        const int pn = p + 4;
        int s_nxt = 0; float as_nxt = 0.f;
        if (pn < e) {                      // prefetch next edge's chain
            s_nxt = csr[pn];
            as_nxt = as_b[s_nxt * H + head];
        }
        float ev = as_cur + ad_n;
        ev = ev > 0.f ? ev : NEG_SLOPE * ev;
        float mn = fmaxf(m, ev);
        float sc = __expf(m - mn);         // 1 if max unchanged; 0 on first edge
        float wv = __expf(ev - mn);
        m = mn;
        const float4 hv = *(const float4*)(h + (size_t)s_cur * 64 + c4 * 4);
        den = fmaf(den, sc, wv);
        acc.x = fmaf(acc.x, sc, wv * hv.x);
        acc.y = fmaf(acc.y, sc, wv * hv.y);
        acc.z = fmaf(acc.z, sc, wv * hv.z);
        acc.w = fmaf(acc.w, sc, wv * hv.w);
        p = pn; s_cur = s_nxt; as_cur = as_nxt;
    }
    // combine quarters (align maxes, then butterfly-sum over lane bits 4,5)
    float m2 = fmaxf(m, __shfl_xor(m, 16));
    float mt = fmaxf(m2, __shfl_xor(m2, 32));
    float sc = __expf(m - mt);             // 0 for empty quarters (m = -1e30)
    den *= sc; acc.x *= sc; acc.y *= sc; acc.z *= sc; acc.w *= sc;
    den += __shfl_xor(den, 16); den += __shfl_xor(den, 32);
    acc.x += __shfl_xor(acc.x, 16); acc.x += __shfl_xor(acc.x, 32);
    acc.y += __shfl_xor(acc.y, 16); acc.y += __shfl_xor(acc.y, 32);
    acc.z += __shfl_xor(acc.z, 16); acc.z += __shfl_xor(acc.z, 32);
    acc.w += __shfl_xor(acc.w, 16); acc.w += __shfl_xor(acc.w, 32);
    if (q == 0) {
        float inv = 1.f / (den + 1e-16f);
        float4 r;
        r.x = acc.x * inv + bias[c4 * 4 + 0];
        r.y = acc.y * inv + bias[c4 * 4 + 1];
        r.z = acc.z * inv + bias[c4 * 4 + 2];
        r.w = acc.w * inv + bias[c4 * 4 + 3];
        if (ELU) {
            r.x = r.x > 0.f ? r.x : expm1f(r.x);
            r.y = r.y > 0.f ? r.y : expm1f(r.y);
            r.z = r.z > 0.f ? r.z : expm1f(r.z);
            r.w = r.w > 0.f ? r.w : expm1f(r.w);
        }
        *(float4*)(out + (size_t)node * 64 + c4 * 4) = r;
    }
}

// ---------------- launch ----------------

extern "C" void kernel_launch(void* const* d_in, const int* in_sizes, int n_in,
                              void* d_out, int out_size, void* d_ws, size_t ws_size,
                              hipStream_t stream) {
    const float* x   = (const float*)d_in[0];
    const int*   idx = (const int*)d_in[1];
    const float* W0  = (const float*)d_in[2];
    const float* as0 = (const float*)d_in[3];
    const float* ad0 = (const float*)d_in[4];
    const float* b0  = (const float*)d_in[5];
    const float* W1  = (const float*)d_in[6];
    const float* as1 = (const float*)d_in[7];
    const float* ad1 = (const float*)d_in[8];
    const float* b1  = (const float*)d_in[9];
    const float* W2  = (const float*)d_in[10];
    const float* as2 = (const float*)d_in[11];
    const float* ad2 = (const float*)d_in[12];
    const float* b2  = (const float*)d_in[13];
    float* out = (float*)d_out;

    const int n    = in_sizes[0] / 128;   // 50000
    const int E    = in_sizes[1] / 2;     // 800000
    const int etot = E + n;

    char* p = (char*)d_ws;
    auto alloc = [&](size_t bytes) {
        char* r = p;
        p += (bytes + 255) & ~(size_t)255;
        return r;
    };
    int*   off   = (int*)alloc((size_t)(n + 1) * 4);
    int*   csr   = (int*)alloc((size_t)etot * 4);
    int*   ghist = (int*)alloc(256 * 4);
    int*   goff  = (int*)alloc(257 * 4);
    int*   gcur  = (int*)alloc(256 * 4);
    float* asb   = (float*)alloc((size_t)n * 4 * 4);
    float* adb   = (float*)alloc((size_t)n * 4 * 4);
    float* hA    = (float*)alloc((size_t)n * 64 * 4);
    // buf (6.8 MB of packed (dst,src)) aliases hA: dead before gemm writes hA.
    unsigned long long* buf = (unsigned long long*)hA;
    // d_out doubles as the inter-layer activation buffer (N*64 floats).

    const int nb_l1 = (etot + L1_CHUNK - 1) / L1_CHUNK;  // 208
    const int nb_l2 = (n + 255) / 256;                   // 196
    const int nb_g  = (n + 15) / 16;   // gemm: 16 nodes / block
    const int nb_w  = (n + 3) / 4;     // agg: 4 nodes (waves) / block

    // CSR build via two-level partition (every call; ws re-poisoned 0xAA)
    hipMemsetAsync(ghist, 0, 256 * 4, stream);
    k_l1hist<<<nb_l1, 256, 0, stream>>>(idx, ghist, E, etot);
    k_scan256<<<1, 256, 0, stream>>>(ghist, goff, gcur);
    k_l1scatter<<<nb_l1, 256, 0, stream>>>(idx, gcur, buf, E, etot);
    k_l2build<<<nb_l2, 256, 0, stream>>>(buf, goff, off, csr, n, etot);

    // layer 0: 128 -> (4,16), concat, ELU   (x -> hA -> out)
    k_gemm_alpha<128, 4, 16><<<nb_g, 256, 0, stream>>>(x, W0, as0, ad0, hA, asb, adb, n);
    k_agg<4, true><<<nb_w, 256, 0, stream>>>(hA, asb, adb, off, csr, b0, out, n);

    // layer 1: 64 -> (4,16), concat, ELU    (out -> hA -> out)
    k_gemm_alpha<64, 4, 16><<<nb_g, 256, 0, stream>>>(out, W1, as1, ad1, hA, asb, adb, n);
    k_agg<4, true><<<nb_w, 256, 0, stream>>>(hA, asb, adb, off, csr, b1, out, n);

    // layer 2: 64 -> (1,64), mean(=identity), no ELU   (out -> hA -> out)
    k_gemm_alpha<64, 1, 64><<<nb_g, 256, 0, stream>>>(out, W2, as2, ad2, hA, asb, adb, n);
    k_agg<1, false><<<nb_w, 256, 0, stream>>>(hA, asb, adb, off, csr, b2, out, n);
}